// Round 6
// baseline (239.732 us; speedup 1.0000x reference)
//
#include <hip/hip_runtime.h>

// Xonv2D: location-dependent 3x3 conv.
//   x:       (B=4, CIN=16, H=128, W=128)  fp32   -- 4 MB, L2-resident
//   weights: (H, W, COUT=16, CIN=16, 3, 3) fp32  -- 151 MB, read-once stream
//   bias:    (H, W, COUT) fp32
//   out:     (B, COUT, H, W) fp32
//
// V11: contiguous-front site mapping -- test DRAM row-locality hypothesis.
//  V5-V10 invariance table: weight supply pinned at ~2.8 B/cy/CU (1.8 TB/s)
//  across occupancy 8-16 w/CU, DMA vs reg vs NT staging, depth 1-2, counted
//  vs drained waits, 92 vs 400 lines/site. Every demand-side hypothesis is
//  falsified. The never-varied axis: CROSS-CU ADDRESS ORDER. All versions
//  gave each wave a private contiguous region -> controllers see ~2048
//  scattered streams -> every DRAM access is a row MISS. m13's 6.3 TB/s
//  pattern interleaves concurrent waves on consecutive blocks -> per-channel
//  sequential order -> row hits (2-4x DRAM factor = the unexplained gap).
//  V11 = V8's exact per-site flow with one change: site(s) = s*2048 + g
//  (g = global wave id). All 2048 waves at step s read ONE contiguous
//  18.9 MB window, 9KB-interleaved sequential. 512 blocks, all resident,
//  no tail. XCD banding dropped (read-once stream: front > L2 locality).
//  A/B: V8 = 90.3us. H_row true -> 35-55us; flat ~90 -> declare ceiling.
//
// Kept from V8/V10 (verified): DMA weight burst is the newest vmem at every
// wait point (coop-x issued before it; counted vmcnt(9)/vmcnt(1) waits, only
// the last iteration drains); coop-x stage (192 unique f4 in 3 loads, LDS
// broadcast consumption -- compute phase is vmem-free); per-lane (o,g)
// 36-float fragment via ds_read_b128; wave-uniform w-border path + h
// clamp-and-zero; butterfly reduce; single store. No barriers anywhere.

#define HWD   128
#define CIND  16
#define COUTD 16
#define BATCH 4
#define SPW   8     // steps per wave; site = s*2048 + g
#define WPB   4     // waves per block

typedef float f4  __attribute__((ext_vector_type(4)));
typedef float f4u __attribute__((ext_vector_type(4), aligned(4)));

// async DMA: 16B per lane, LDS dest = wave-uniform base + lane*16 (linear).
__device__ __forceinline__ void gload_lds16(const f4* gsrc, f4* ldst) {
    __builtin_amdgcn_global_load_lds(
        (const __attribute__((address_space(1))) unsigned int*)gsrc,
        (__attribute__((address_space(3))) unsigned int*)ldst,
        16, 0, 0);
}

__global__ __launch_bounds__(256) void xonv2d_kernel(
    const float* __restrict__ x,
    const float* __restrict__ wts,
    const float* __restrict__ bias,
    float* __restrict__ out)
{
    __shared__ f4 wbuf[WPB][576];    // 9216 B/wave: weight buffer
    __shared__ f4 xslot[WPB][192];   // 3072 B/wave: x window, zero-padded

    const int lane = threadIdx.x & 63;
    const int wave = threadIdx.x >> 6;

    // Global wave id: concurrent waves are CONSECUTIVE -> at step s the
    // 2048 waves read sites [s*2048,(s+1)*2048) = contiguous 18.9 MB front.
    const int g_id = blockIdx.x * WPB + wave;   // 0..2047

    const int o  = lane & 15;    // output channel
    const int g  = lane >> 4;    // channel group: c in [4g, 4g+4)
    const int c0 = g * 4;

    // coop-x decode: element S = lane + 64*j holds the f4 window (cols
    // w-1..w+2) of batch b=S/48, channel c=(S%48)/3, row r=S%3; slot==S.
    int sb[3], sc[3], sr[3];
    #pragma unroll
    for (int j = 0; j < 3; ++j) {
        const int S = lane + 64 * j;
        sb[j] = S / 48;
        const int u = S - sb[j] * 48;
        sc[j] = u / 3;
        sr[j] = u - sc[j] * 3;
    }

    // ---- prologue: DMA step-0 weights (the only vmem in flight) ----
    {
        const f4* gw = (const f4*)wts + (size_t)g_id * 576;
        #pragma unroll
        for (int j = 0; j < 9; ++j)
            gload_lds16(gw + j * 64 + lane, &wbuf[wave][j * 64]);
    }

    #pragma unroll 1
    for (int s = 0; s < SPW; ++s) {
        const int site = s * 2048 + g_id;
        const int h = site >> 7;
        const int w = site & 127;

        // A: this step's weight DMA landed. (s>0: the single newer op is
        // last step's store; in-order retirement makes vmcnt(1) exact.)
        if (s == 0) asm volatile("s_waitcnt vmcnt(0)" ::: "memory");
        else        asm volatile("s_waitcnt vmcnt(1)" ::: "memory");
        __builtin_amdgcn_sched_barrier(0);

        // B: (o,g) 36-float fragment -> regs; buffer free after lgkm(0).
        f4 wv[9];
        {
            const f4* lp = &wbuf[wave][o * 36 + g * 9];
            #pragma unroll
            for (int j = 0; j < 9; ++j) wv[j] = lp[j];   // ds_read_b128
        }
        asm volatile("s_waitcnt lgkmcnt(0)" ::: "memory");
        __builtin_amdgcn_sched_barrier(0);
        const float* wf = (const float*)wv;

        // C: coop x stage (3 f4/lane = the site's 192 unique f4) + bias.
        //    Issued BEFORE the prefetch so their waits never drain it.
        f4 xr[3];
        const bool wfast = (w >= 1) && (w <= HWD - 3);
        #pragma unroll
        for (int j = 0; j < 3; ++j) {
            const int hy   = h + sr[j] - 1;
            const bool okh = (unsigned)hy < (unsigned)HWD;
            const int hyc  = okh ? hy : 0;
            const float* xb = x + ((size_t)(sb[j] * CIND + sc[j]) * HWD + hyc) * HWD;
            if (wfast) {
                f4 v = *(const f4u*)(xb + (w - 1));
                xr[j] = okh ? v : (f4){0.f, 0.f, 0.f, 0.f};
            } else {
                f4 v;
                #pragma unroll
                for (int jj = 0; jj < 4; ++jj) {
                    const int cw = w - 1 + jj;
                    const bool ok = okh && ((unsigned)cw < (unsigned)HWD);
                    v[jj] = ok ? xb[cw] : 0.f;
                }
                xr[j] = v;
            }
        }
        const float bv = bias[(size_t)site * COUTD + o];
        __builtin_amdgcn_sched_barrier(0);

        // D: prefetch next step's weights into the SAME buffer (frag is in
        //    regs; lgkm(0) above ordered the reads before this DMA).
        if (s + 1 < SPW) {
            const f4* gw = (const f4*)wts + (size_t)(site + 2048) * 576;
            #pragma unroll
            for (int j = 0; j < 9; ++j)
                gload_lds16(gw + j * 64 + lane, &wbuf[wave][j * 64]);
        }
        __builtin_amdgcn_sched_barrier(0);

        // E: x+bias ready; the 9 newest (weight prefetch) stay in flight
        //    across the entire compute phase and the next step's loads.
        if (s + 1 < SPW) asm volatile("s_waitcnt vmcnt(9)" ::: "memory");
        else             asm volatile("s_waitcnt vmcnt(0)" ::: "memory");
        __builtin_amdgcn_sched_barrier(0);

        // F: publish x to LDS, compute entirely from LDS (lgkm only).
        #pragma unroll
        for (int j = 0; j < 3; ++j)
            xslot[wave][lane + 64 * j] = xr[j];          // ds_write_b128

        float acc[BATCH] = {0.f, 0.f, 0.f, 0.f};
        #pragma unroll
        for (int cc = 0; cc < 4; ++cc) {
            #pragma unroll
            for (int b = 0; b < BATCH; ++b) {
                // 16 o-lanes read the same address: LDS broadcast, free.
                const f4* xp = &xslot[wave][(b * CIND + c0 + cc) * 3];
                const f4 r0 = xp[0];
                const f4 r1 = xp[1];
                const f4 r2 = xp[2];
                const float* wr = wf + cc * 9;
                acc[b] = fmaf(r0.x, wr[0], acc[b]);
                acc[b] = fmaf(r0.y, wr[1], acc[b]);
                acc[b] = fmaf(r0.z, wr[2], acc[b]);
                acc[b] = fmaf(r1.x, wr[3], acc[b]);
                acc[b] = fmaf(r1.y, wr[4], acc[b]);
                acc[b] = fmaf(r1.z, wr[5], acc[b]);
                acc[b] = fmaf(r2.x, wr[6], acc[b]);
                acc[b] = fmaf(r2.y, wr[7], acc[b]);
                acc[b] = fmaf(r2.z, wr[8], acc[b]);
            }
        }

        // ---- butterfly reduce over the 4 c-groups ----
        float r[BATCH];
        #pragma unroll
        for (int b = 0; b < BATCH; ++b) {
            float v = acc[b];
            v += __shfl_xor(v, 32);
            v += __shfl_xor(v, 16);
            r[b] = v;
        }

        // lane (g,o) stores batch b = g: one store, all 64 lanes active
        const float vout = (g == 0) ? r[0] : (g == 1) ? r[1] : (g == 2) ? r[2] : r[3];
        out[((size_t)(g * COUTD + o)) * (HWD * HWD) + h * HWD + w] = vout + bv;
    }
}

extern "C" void kernel_launch(void* const* d_in, const int* in_sizes, int n_in,
                              void* d_out, int out_size, void* d_ws, size_t ws_size,
                              hipStream_t stream) {
    const float* x    = (const float*)d_in[0];
    const float* wts  = (const float*)d_in[1];
    const float* bias = (const float*)d_in[2];
    float* out = (float*)d_out;

    // 2048 waves = 512 blocks x 4 waves; 8 steps x 2048 = 16384 sites.
    // 48KB LDS -> all 512 blocks resident (capacity 3/CU): zero tail.
    const int blocks = 2048 / WPB;
    xonv2d_kernel<<<blocks, WPB * 64, 0, stream>>>(x, wts, bias, out);
}

// Round 7
// 228.106 us; speedup vs baseline: 1.0510x; 1.0510x over previous
//
#include <hip/hip_runtime.h>

// Xonv2D: location-dependent 3x3 conv.
//   x:       (B=4, CIN=16, H=128, W=128)  fp32   -- 4 MB, L2-resident
//   weights: (H, W, COUT=16, CIN=16, 3, 3) fp32  -- 151 MB, read-once stream
//   bias:    (H, W, COUT) fp32
//   out:     (B, COUT, H, W) fp32
//
// V12: direct-fragment register streaming -- the m13-shaped kernel.
//  V5-V11 falsification table: supply pinned ~1.8 TB/s across occupancy
//  (8-16 w/CU), staging (DMA/reg/NT), lines/site (400 vs 92), waits, and
//  cross-CU address order. The never-varied axis: EFFECTIVE PIPELINE DEPTH.
//  Every version did wait(9) -> LDS transpose round-trip -> compute ->
//  issue: <=1 site in flight/wave, ~600cy cover vs multi-1000cy loaded
//  latency (V9's depth-2 collapsed: VGPR=72 shows the compiler sank the
//  staged loads into their LDS-write uses). m13's 6.3 TB/s is a register-
//  consumed stream with a deep rotating load window -- never built here
//  because the (o,g) fragment "needed" a transpose. It doesn't:
//    lane l := (o = l>>2, g = l&3)  =>  fragment = floats [36l, 36l+36)
//    = f4 [9l, 9l+9) -- 9 CONSECUTIVE f4s per lane. 9 plain dwordx4 loads
//  (inter-lane stride 144B) land the fragment directly in FMA-input regs.
//  No wbuf, no ds_write/ds_read, no lgkm(0), no WAR hazard. Line count
//  unchanged: instr 0 touches the site's 72 lines (16B each), instrs 1-8
//  hit L1 (9KB << 32KB). Depth-2 rotation wa/wb: prefetch for site s+2
//  issued at END of iter s -> a full iteration of latency cover; loads are
//  compiler-visible register deps (can't be sunk past the counted waits;
//  correctness-waits auto-inserted on first register use).
//  Loop is weight-pure: x staged once per block (V10 slab), bias
//  prefetched, stores batched post-loop. Target VGPR <=128 -> 16 waves/CU.
//
// Kept (verified): V10 x-slab w/ zero-padding as conv pad (no edge branches),
// 2-way-free LDS broadcast reads, XCD banding (row-aligned 32-site blocks),
// butterfly reduce (now over adjacent lanes: xor 1, xor 2), batched dwordx4
// stores, counted vmcnt(9) waits -- only the last iteration drains.

#define HWD   128
#define CIND  16
#define COUTD 16
#define SPW   8     // sites per wave (one run, same row)
#define WPB   4     // waves per block -> 32 consecutive sites per block
#define XROWF 44    // xs row stride in floats (16B-aligned, bank-spread)

typedef float f4  __attribute__((ext_vector_type(4)));
typedef float f4u __attribute__((ext_vector_type(4), aligned(4)));

// One site step. S is a compile-time literal at each expansion; CUR is the
// f4[9] register buffer holding site S's fragment (loaded 2 iters ago).
#define SITE_ITER(S, CUR)                                                     \
  {                                                                           \
    /* site S's 9 loads are the oldest outstanding; the only newer ops   */   \
    /* are site S+1's 9 (prefetched last iter). Counted wait: exact.     */   \
    if ((S) == SPW - 1) asm volatile("s_waitcnt vmcnt(0)" ::: "memory");      \
    else                asm volatile("s_waitcnt vmcnt(9)" ::: "memory");      \
    __builtin_amdgcn_sched_barrier(0);                                        \
    const float* wf = (const float*)(CUR);                                    \
    const int slot0 = wv * 8 + (S) + 3;                                       \
    float acc0 = 0.f, acc1 = 0.f, acc2 = 0.f, acc3 = 0.f;                     \
    _Pragma("unroll")                                                         \
    for (int cc = 0; cc < 4; ++cc) {                                          \
      _Pragma("unroll")                                                       \
      for (int r = 0; r < 3; ++r) {                                           \
        const float* wr = wf + cc * 9 + r * 3;                                \
        _Pragma("unroll")                                                     \
        for (int b = 0; b < 4; ++b) {                                         \
          const int R = (b * CIND + c0 + cc) * 3 + r;                         \
          const float* xp = &xs[R * XROWF + slot0];                           \
          float* ac = (b == 0) ? &acc0 : (b == 1) ? &acc1                     \
                    : (b == 2) ? &acc2 : &acc3;                               \
          *ac = fmaf(xp[0], wr[0], *ac);                                      \
          *ac = fmaf(xp[1], wr[1], *ac);                                      \
          *ac = fmaf(xp[2], wr[2], *ac);                                      \
        }                                                                     \
      }                                                                       \
    }                                                                         \
    /* butterfly over the 4 c-groups (adjacent lanes: bits 0,1) */            \
    acc0 += __shfl_xor(acc0, 1); acc0 += __shfl_xor(acc0, 2);                 \
    acc1 += __shfl_xor(acc1, 1); acc1 += __shfl_xor(acc1, 2);                 \
    acc2 += __shfl_xor(acc2, 1); acc2 += __shfl_xor(acc2, 2);                 \
    acc3 += __shfl_xor(acc3, 1); acc3 += __shfl_xor(acc3, 2);                 \
    const float vout = (g == 0) ? acc0 : (g == 1) ? acc1                      \
                     : (g == 2) ? acc2 : acc3;                                \
    rs[(S)] = vout + bvr[(S)];                                                \
    __builtin_amdgcn_sched_barrier(0);                                        \
    /* prefetch site S+2 into the just-consumed buffer: issued at the    */   \
    /* end of the iter, so it has a FULL iteration of cover before its   */   \
    /* wait at iter S+2's entry. Newest vmem at every wait point.        */   \
    if ((S) + 2 < SPW) {                                                      \
      const f4* gp = gwl + (size_t)((S) + 2) * 576;                           \
      _Pragma("unroll")                                                       \
      for (int j = 0; j < 9; ++j) (CUR)[j] = gp[j];                           \
    }                                                                         \
    __builtin_amdgcn_sched_barrier(0);                                        \
  }

__global__ __launch_bounds__(256) void xonv2d_kernel(
    const float* __restrict__ x,
    const float* __restrict__ wts,
    const float* __restrict__ bias,
    float* __restrict__ out)
{
    __shared__ float xs[192 * XROWF];   // 33792 B: block x slab (only LDS)

    const int tid  = threadIdx.x;
    const int lane = tid & 63;
    const int wv   = tid >> 6;

    // XCD banding: XCD k = blockIdx%8 handles sites [k*2048,(k+1)*2048).
    // Bands are 16 whole rows; blocks stay row-aligned (32 | 128).
    const int xcd  = blockIdx.x & 7;
    const int idx  = blockIdx.x >> 3;          // 0..63 within band
    const int sblk = xcd * 2048 + idx * 32;    // block's first site
    const int h    = sblk >> 7;
    const int w0b  = sblk & 127;               // 0,32,64,96
    const int w0   = w0b + wv * 8;             // wave's first site col

    const int o  = lane >> 2;    // output channel   (direct-fragment map)
    const int g  = lane & 3;     // channel group: c in [4g,4g+4)
    const int c0 = g * 4;

    // ---- coop x stage: 192 rows x 10 f4 (cols w0b-4..w0b+35), 256 thr ----
    // OOB f4s written as zeros: the padding IS the conv zero-pad.
    #pragma unroll
    for (int j = 0; j < 8; ++j) {
        const int t = tid + 256 * j;
        if (t < 1920) {
            const int R = t / 10, q = t - R * 10;
            const int b = R / 48;
            const int u = R - b * 48;
            const int c = u / 3, r = u - c * 3;
            const int hy = h + r - 1;
            const int cb = w0b - 4 + 4 * q;
            f4 v = {0.f, 0.f, 0.f, 0.f};
            if (((unsigned)hy < (unsigned)HWD) & ((unsigned)cb <= (unsigned)(HWD - 4)))
                v = *(const f4u*)(x + ((size_t)(b * CIND + c) * HWD + hy) * HWD + cb);
            *(f4*)&xs[R * XROWF + q * 4] = v;
        }
    }

    // ---- bias prefetch: the run's 8 values per lane ----
    float bvr[SPW];
    #pragma unroll
    for (int s = 0; s < SPW; ++s)
        bvr[s] = bias[(size_t)(sblk + wv * 8 + s) * COUTD + o];

    // ---- lane's fragment base: site*576 + 9*lane (f4 units) ----
    const f4* gwl = (const f4*)wts + (size_t)(sblk + wv * 8) * 576 + 9 * lane;

    // ---- prologue: sites 0 and 1 into the two register buffers ----
    f4 wa[9], wb[9];
    #pragma unroll
    for (int j = 0; j < 9; ++j) wa[j] = gwl[j];
    #pragma unroll
    for (int j = 0; j < 9; ++j) wb[j] = gwl[576 + j];

    __syncthreads();   // x slab visible (drains the prologue loads too; once)

    float rs[SPW];     // run outputs, static-indexed (macro literals)

    SITE_ITER(0, wa)   // consume site0, prefetch site2 -> wa
    SITE_ITER(1, wb)   // consume site1, prefetch site3 -> wb
    SITE_ITER(2, wa)
    SITE_ITER(3, wb)
    SITE_ITER(4, wa)
    SITE_ITER(5, wb)
    SITE_ITER(6, wa)   // no prefetch (S+2 >= 8)
    SITE_ITER(7, wb)

    // ---- batched store: 8 consecutive w per lane = 2 dwordx4 ----
    // lane (o,g) stores batch b = g, channel o.
    float* ob = out + ((size_t)(g * COUTD + o)) * (HWD * HWD) + h * HWD + w0;
    f4 sA = {rs[0], rs[1], rs[2], rs[3]};
    f4 sB = {rs[4], rs[5], rs[6], rs[7]};
    *(f4*)(ob)     = sA;
    *(f4*)(ob + 4) = sB;
}

extern "C" void kernel_launch(void* const* d_in, const int* in_sizes, int n_in,
                              void* d_out, int out_size, void* d_ws, size_t ws_size,
                              hipStream_t stream) {
    const float* x    = (const float*)d_in[0];
    const float* wts  = (const float*)d_in[1];
    const float* bias = (const float*)d_in[2];
    float* out = (float*)d_out;

    // 16384 sites / 32 per block = 512 blocks of 256 threads.
    // 33.8KB LDS; target VGPR <=128 -> up to 4 blocks/CU (16 waves/CU).
    const int blocks = (HWD * HWD) / (WPB * SPW);
    xonv2d_kernel<<<blocks, WPB * 64, 0, stream>>>(x, wts, bias, out);
}